// Round 7
// baseline (260.254 us; speedup 1.0000x reference)
//
#include <hip/hip_runtime.h>
#include <hip/hip_bf16.h>
#include <math.h>

// GAT structural encoder: out = x + h1 + h2
//   h1 = relu(gat(x;  W1,a_src1,a_dst1,b1))
//   h2 = relu(gat(h1; W2,a_src2,a_dst2,b2))
// Round-7 design:
//  - CSR build in two phases: (1) bucket edges into 1024-dst coarse buckets with
//    LDS histograms + range claiming (sequential-run writes), (2) one block per
//    bucket builds csr_pad with LDS counters -> csr lines dirtied once (was 45MB
//    of per-XCD write-back amplification from the naive atomic scatter).
//  - phase 2 grid-fused with gemm1 (independent work, co-resident).
//  - gemm2 fused into agg1: h2 row r depends only on h1 row r. Block aggregates
//    32 dsts -> h1 tile in LDS -> MFMA vs wp2 (from L2). gemm2 dispatch gone.
//  - GEMM via v_mfma_f32_16x16x32_bf16; W pre-packed fragment-order; 9th col-tile
//    = [W@a_src | W@a_dst] so logits fall out of the MFMA accumulators.
// Fragment layout (verified refs in guide): A: row=lane&15, k=8*(lane>>4)+e;
// B: col=lane&15, k=8*(lane>>4)+e; C/D: col=lane&15, row=4*(lane>>4)+reg.

constexpr int D = 128;
constexpr int CAP = 64;       // max in-degree (multinomial mean 16, max ~33)
constexpr int WPACK = 18432;  // packed W elems: 16384 (W) + 2048 (Va)
constexpr int NBMAX = 64;     // max coarse buckets
constexpr int BCAP = 24576;   // edges per coarse bucket capacity (mean 16384)
constexpr int EPB = 4096;     // edges per phase-1 block

using bf16x8 = __attribute__((ext_vector_type(8))) short;
using f32x4 = __attribute__((ext_vector_type(4))) float;

static __device__ __forceinline__ float lrelu(float v) {
  return v > 0.f ? v : 0.2f * v;
}

static __device__ __forceinline__ ushort bfbits(float f) {
  __hip_bfloat16 b = __float2bfloat16(f);
  return *reinterpret_cast<ushort*>(&b);
}

static __device__ __forceinline__ float bf2f(ushort u) {
  union { unsigned int u; float f; } c;
  c.u = (unsigned int)u << 16;
  return c.f;
}

// ---------------- K1: pack W1/W2 into fragment order; zero bucket_cnt --------
// idx<16384: Wp[ks][g][ct][c][e] = W[ks*32+g*8+e][ct*16+c]
// idx>=16384: Va block [ks][g][c][e]: c<8 -> head c of W@a_src; c>=8 -> W@a_dst
__global__ void pack_all_kernel(const float* __restrict__ W1, const float* __restrict__ as1,
                                const float* __restrict__ ad1, ushort* __restrict__ wp1,
                                const float* __restrict__ W2, const float* __restrict__ as2,
                                const float* __restrict__ ad2, ushort* __restrict__ wp2,
                                int* __restrict__ bucket_cnt) {
  int t = blockIdx.x * blockDim.x + threadIdx.x;
  if (t < NBMAX) bucket_cnt[t] = 0;
  const float *W, *as_, *ad_;
  ushort* wp;
  int idx;
  if (t < WPACK) {
    W = W1; as_ = as1; ad_ = ad1; wp = wp1; idx = t;
  } else if (t < 2 * WPACK) {
    W = W2; as_ = as2; ad_ = ad2; wp = wp2; idx = t - WPACK;
  } else {
    return;
  }
  if (idx < 16384) {
    int e = idx & 7, c = (idx >> 3) & 15, ct = (idx >> 7) & 7, g = (idx >> 10) & 3,
        ks = idx >> 12;
    int k = ks * 32 + g * 8 + e, n = ct * 16 + c;
    wp[idx] = bfbits(W[k * 128 + n]);
  } else {
    int j = idx - 16384;
    int e = j & 7, c = (j >> 3) & 15, g = (j >> 7) & 3, ks = j >> 9;
    int k = ks * 32 + g * 8 + e;
    int h = c & 7;
    const float* a = (c >> 3) ? ad_ : as_;
    float s = 0.f;
    #pragma unroll
    for (int cc = 0; cc < 16; ++cc) s += W[k * 128 + h * 16 + cc] * a[h * 16 + cc];
    wp[idx] = bfbits(s);
  }
}

// ---------------- K2: phase-1 bucket scatter ----------------
// Pack (dstLow10 << 16 | row16) into per-bucket regions; runs are sequential.
__global__ __launch_bounds__(256) void bucket_kernel(
    const int* __restrict__ row, const int* __restrict__ col,
    int* __restrict__ bucket_cnt, unsigned int* __restrict__ bkt, int E, int NB) {
  __shared__ int hist[NBMAX];
  __shared__ int base_s[NBMAX];
  int tid = threadIdx.x;
  if (tid < NBMAX) hist[tid] = 0;
  __syncthreads();
  int e0 = blockIdx.x * EPB;
  unsigned int uv[16];
  int bb[16], rr[16];
  #pragma unroll
  for (int j = 0; j < 16; ++j) {
    int e = e0 + j * 256 + tid;
    bb[j] = -1; uv[j] = 0; rr[j] = 0;
    if (e < E) {
      int c = col[e], r = row[e];
      bb[j] = c >> 10;
      uv[j] = ((unsigned int)(c & 1023) << 16) | (unsigned int)r;
      rr[j] = atomicAdd(&hist[bb[j]], 1);
    }
  }
  __syncthreads();
  if (tid < NB) base_s[tid] = atomicAdd(&bucket_cnt[tid], hist[tid]);
  __syncthreads();
  #pragma unroll
  for (int j = 0; j < 16; ++j) {
    if (bb[j] >= 0) {
      int pos = base_s[bb[j]] + rr[j];
      if (pos < BCAP) bkt[(size_t)bb[j] * BCAP + pos] = uv[j];
    }
  }
}

// ---------------- K3: phase-2 CSR build (blocks < NB) + gemm1 ----------------
__global__ __launch_bounds__(256) void csr_gemm_kernel(
    const float* __restrict__ X, const ushort* __restrict__ Wp,
    ushort* __restrict__ Hf, ushort* __restrict__ asrc, float* __restrict__ adst,
    int N, const unsigned int* __restrict__ bkt, const int* __restrict__ bucket_cnt,
    int* __restrict__ cnt, ushort* __restrict__ csr_pad, int NB) {
  __shared__ ushort Wl[WPACK];  // 36 KB (phase-2 blocks alias 4 KB of it)
  int tid = threadIdx.x;
  if ((int)blockIdx.x < NB) {
    int b = blockIdx.x;
    int* lcnt = (int*)Wl;
    for (int i = tid; i < 1024; i += 256) lcnt[i] = 0;
    __syncthreads();
    int ce = min(bucket_cnt[b], BCAP);
    const unsigned int* bp = bkt + (size_t)b * BCAP;
    for (int i = tid; i < ce; i += 256) {
      unsigned int u = bp[i];
      int dl = u >> 16;
      int p = atomicAdd(&lcnt[dl], 1);
      if (p < CAP) csr_pad[((size_t)((b << 10) + dl)) * CAP + p] = (ushort)(u & 0xffffu);
    }
    __syncthreads();
    int nd = min(1024, N - (b << 10));
    for (int i = tid; i < nd; i += 256) cnt[(b << 10) + i] = lcnt[i];
    return;
  }

  // ---- gemm1: X(f32) @ W1 -> Hf(bf16) + logits ----
  for (int i = tid; i < WPACK / 8; i += 256)
    *(uint4*)&Wl[i * 8] = *(const uint4*)&Wp[i * 8];
  __syncthreads();

  int lane = tid & 63, w = tid >> 6;
  int g = lane >> 4, c = lane & 15;
  int rt0 = ((int)blockIdx.x - NB) * 128 + w * 32;

  f32x4 acc[2][9];
  #pragma unroll
  for (int rt = 0; rt < 2; ++rt)
    #pragma unroll
    for (int ct = 0; ct < 9; ++ct) acc[rt][ct] = (f32x4)0.f;

  #pragma unroll
  for (int ks = 0; ks < 4; ++ks) {
    bf16x8 a[2];
    #pragma unroll
    for (int rt = 0; rt < 2; ++rt) {
      int r = rt0 + rt * 16 + c;
      if (r < N) {
        const float* xp = &X[(size_t)r * D + ks * 32 + g * 8];
        float4 x0 = *(const float4*)xp;
        float4 x1 = *(const float4*)(xp + 4);
        bf16x8 t;
        t[0] = (short)bfbits(x0.x); t[1] = (short)bfbits(x0.y);
        t[2] = (short)bfbits(x0.z); t[3] = (short)bfbits(x0.w);
        t[4] = (short)bfbits(x1.x); t[5] = (short)bfbits(x1.y);
        t[6] = (short)bfbits(x1.z); t[7] = (short)bfbits(x1.w);
        a[rt] = t;
      } else {
        a[rt] = (bf16x8)(short)0;
      }
    }
    #pragma unroll
    for (int ct = 0; ct < 9; ++ct) {
      const ushort* bp = (ct < 8)
          ? &Wl[(size_t)(((ks * 4 + g) * 8 + ct) * 16 + c) * 8]
          : &Wl[16384 + (size_t)((ks * 4 + g) * 16 + c) * 8];
      bf16x8 b = *(const bf16x8*)bp;
      acc[0][ct] = __builtin_amdgcn_mfma_f32_16x16x32_bf16(a[0], b, acc[0][ct], 0, 0, 0);
      acc[1][ct] = __builtin_amdgcn_mfma_f32_16x16x32_bf16(a[1], b, acc[1][ct], 0, 0, 0);
    }
  }

  #pragma unroll
  for (int rt = 0; rt < 2; ++rt) {
    #pragma unroll
    for (int j = 0; j < 4; ++j) {
      int r = rt0 + rt * 16 + g * 4 + j;
      if (r >= N) continue;
      #pragma unroll
      for (int ct = 0; ct < 8; ++ct)
        Hf[(size_t)r * D + ct * 16 + c] = bfbits(acc[rt][ct][j]);
      float lv = acc[rt][8][j];
      if (c < 8) asrc[r * 8 + c] = bfbits(lv);
      else adst[r * 8 + (c - 8)] = lv;
    }
  }
}

// ---------------- shared gather: softmax-weighted neighbor sum ----------------
static __device__ __forceinline__ void gather_node(
    const ushort* __restrict__ Hf, const ushort* __restrict__ asrc, float adst_h,
    const int* __restrict__ cnt, const ushort* __restrict__ csr_pad,
    int dst, int h, int d0, float& accx, float& accy, float& wsum) {
  float ws = __expf(lrelu(bf2f(asrc[dst * 8 + h]) + adst_h));  // self loop
  ushort2 fs = *(const ushort2*)&Hf[(size_t)dst * D + d0];
  accx = ws * bf2f(fs.x); accy = ws * bf2f(fs.y); wsum = ws;
  int cn = min(cnt[dst], CAP);
  const ushort* cp = csr_pad + (size_t)dst * CAP;
  int i = 0;
  for (; i + 4 <= cn; i += 4) {
    ushort4 s4 = *(const ushort4*)(cp + i);
    float l0 = bf2f(asrc[(int)s4.x * 8 + h]);
    float l1 = bf2f(asrc[(int)s4.y * 8 + h]);
    float l2 = bf2f(asrc[(int)s4.z * 8 + h]);
    float l3 = bf2f(asrc[(int)s4.w * 8 + h]);
    ushort2 f0 = *(const ushort2*)&Hf[(size_t)s4.x * D + d0];
    ushort2 f1 = *(const ushort2*)&Hf[(size_t)s4.y * D + d0];
    ushort2 f2 = *(const ushort2*)&Hf[(size_t)s4.z * D + d0];
    ushort2 f3 = *(const ushort2*)&Hf[(size_t)s4.w * D + d0];
    float w0 = __expf(lrelu(l0 + adst_h));
    float w1 = __expf(lrelu(l1 + adst_h));
    float w2 = __expf(lrelu(l2 + adst_h));
    float w3 = __expf(lrelu(l3 + adst_h));
    accx += w0 * bf2f(f0.x) + w1 * bf2f(f1.x) + w2 * bf2f(f2.x) + w3 * bf2f(f3.x);
    accy += w0 * bf2f(f0.y) + w1 * bf2f(f1.y) + w2 * bf2f(f2.y) + w3 * bf2f(f3.y);
    wsum += w0 + w1 + w2 + w3;
  }
  for (; i < cn; ++i) {
    int src = cp[i];
    float we = __expf(lrelu(bf2f(asrc[src * 8 + h]) + adst_h));
    ushort2 fv = *(const ushort2*)&Hf[(size_t)src * D + d0];
    accx += we * bf2f(fv.x);
    accy += we * bf2f(fv.y);
    wsum += we;
  }
}

// ---------------- K4: agg1 + fused gemm2 ----------------
// Block = 4 waves, 32 dsts (8 per wave). Phase A: gather -> h1 tile in LDS +
// global h1. Phase B: MFMA h1-tile @ wp2 (B-frags from global/L2).
__global__ __launch_bounds__(256) void agg_gemm_kernel(
    const ushort* __restrict__ Hf1, const ushort* __restrict__ asrc1,
    const float* __restrict__ adst1, const int* __restrict__ cnt,
    const ushort* __restrict__ csr_pad, const float* __restrict__ bias1,
    const ushort* __restrict__ wp2, ushort* __restrict__ h1out,
    ushort* __restrict__ Hf2, ushort* __restrict__ asrc2, float* __restrict__ adst2,
    int N) {
  __shared__ ushort Ht[32][144];  // pad 144: 16B-aligned rows, ~4-way max conflict
  int tid = threadIdx.x, lane = tid & 63, w = tid >> 6;
  int h = lane >> 3, d0 = lane * 2;
  int dst0 = blockIdx.x * 32;

  // ---- phase A: aggregate 8 dsts per wave ----
  for (int i = 0; i < 8; ++i) {
    int trow = w * 8 + i;
    int dst = dst0 + trow;
    float r0 = 0.f, r1 = 0.f;
    if (dst < N) {
      float adh = adst1[dst * 8 + h];
      float ax, ay, wsm;
      gather_node(Hf1, asrc1, adh, cnt, csr_pad, dst, h, d0, ax, ay, wsm);
      float inv = 1.f / (wsm + 1e-16f);
      float2 bv = *(const float2*)&bias1[d0];
      r0 = fmaxf(ax * inv + bv.x, 0.f);
      r1 = fmaxf(ay * inv + bv.y, 0.f);
    }
    ushort2 u;
    u.x = bfbits(r0); u.y = bfbits(r1);
    *(ushort2*)&Ht[trow][d0] = u;
    if (dst < N) *(ushort2*)&h1out[(size_t)dst * D + d0] = u;
  }
  __syncthreads();

  // ---- phase B: gemm2 on the 32-row tile ----
  int g = lane >> 4, c = lane & 15;
  bf16x8 afr[2][4];
  #pragma unroll
  for (int rt = 0; rt < 2; ++rt)
    #pragma unroll
    for (int ks = 0; ks < 4; ++ks)
      afr[rt][ks] = *(const bf16x8*)&Ht[rt * 16 + c][ks * 32 + g * 8];

  // wave w handles col-tiles {w, 4+w}; wave 0 also the Va tile (ct=8)
  f32x4 acc[2][3];
  #pragma unroll
  for (int rt = 0; rt < 2; ++rt)
    #pragma unroll
    for (int ci = 0; ci < 3; ++ci) acc[rt][ci] = (f32x4)0.f;

  #pragma unroll
  for (int ci = 0; ci < 3; ++ci) {
    bool act = (ci < 2) || (w == 0);
    if (!act) continue;
    int ct = (ci == 0) ? w : (ci == 1) ? (4 + w) : 8;
    #pragma unroll
    for (int ks = 0; ks < 4; ++ks) {
      const ushort* bp = (ct < 8)
          ? &wp2[(size_t)(((ks * 4 + g) * 8 + ct) * 16 + c) * 8]
          : &wp2[16384 + (size_t)((ks * 4 + g) * 16 + c) * 8];
      bf16x8 b = *(const bf16x8*)bp;
      acc[0][ci] = __builtin_amdgcn_mfma_f32_16x16x32_bf16(afr[0][ks], b, acc[0][ci], 0, 0, 0);
      acc[1][ci] = __builtin_amdgcn_mfma_f32_16x16x32_bf16(afr[1][ks], b, acc[1][ci], 0, 0, 0);
    }
  }

  #pragma unroll
  for (int ci = 0; ci < 3; ++ci) {
    bool act = (ci < 2) || (w == 0);
    if (!act) continue;
    int ct = (ci == 0) ? w : (ci == 1) ? (4 + w) : 8;
    #pragma unroll
    for (int rt = 0; rt < 2; ++rt) {
      #pragma unroll
      for (int j = 0; j < 4; ++j) {
        int r = rt * 16 + g * 4 + j;
        int dst = dst0 + r;
        if (dst >= N) continue;
        float lv = acc[rt][ci][j];
        if (ct < 8) {
          Hf2[(size_t)dst * D + ct * 16 + c] = bfbits(lv);
        } else {
          if (c < 8) asrc2[dst * 8 + c] = bfbits(lv);
          else adst2[dst * 8 + (c - 8)] = lv;
        }
      }
    }
  }
}

// ---------------- K5: agg2 -> out = x + h1 + h2 ----------------
__global__ __launch_bounds__(256) void aggregate2_kernel(
    const ushort* __restrict__ Hf, const ushort* __restrict__ asrc,
    const float* __restrict__ adst, const int* __restrict__ cnt,
    const ushort* __restrict__ csr_pad, const float* __restrict__ bias,
    const float* __restrict__ xin, const ushort* __restrict__ h1in,
    float* __restrict__ outp, int N) {
  int wid = (blockIdx.x * blockDim.x + threadIdx.x) >> 6;
  if (wid >= N) return;
  int lane = threadIdx.x & 63;
  int h = lane >> 3, d0 = lane * 2;
  int dst = wid;
  float adh = adst[dst * 8 + h];
  float ax, ay, wsm;
  gather_node(Hf, asrc, adh, cnt, csr_pad, dst, h, d0, ax, ay, wsm);
  float inv = 1.f / (wsm + 1e-16f);
  float2 bv = *(const float2*)&bias[d0];
  float r0 = fmaxf(ax * inv + bv.x, 0.f);
  float r1 = fmaxf(ay * inv + bv.y, 0.f);
  float2 xv = *(const float2*)&xin[(size_t)dst * D + d0];
  ushort2 hv = *(const ushort2*)&h1in[(size_t)dst * D + d0];
  *(float2*)&outp[(size_t)dst * D + d0] =
      make_float2(xv.x + bf2f(hv.x) + r0, xv.y + bf2f(hv.y) + r1);
}

extern "C" void kernel_launch(void* const* d_in, const int* in_sizes, int n_in,
                              void* d_out, int out_size, void* d_ws, size_t ws_size,
                              hipStream_t stream) {
  const float* x = (const float*)d_in[0];
  const int* ei = (const int*)d_in[1];
  const float* W1 = (const float*)d_in[3];
  const float* as1 = (const float*)d_in[4];
  const float* ad1 = (const float*)d_in[5];
  const float* b1 = (const float*)d_in[6];
  const float* W2 = (const float*)d_in[7];
  const float* as2 = (const float*)d_in[8];
  const float* ad2 = (const float*)d_in[9];
  const float* b2 = (const float*)d_in[10];
  float* out = (float*)d_out;

  const int N = in_sizes[0] / D;   // 50000 (< 65536: ushort node IDs)
  const int E = in_sizes[1] / 2;
  const int* row = ei;
  const int* col = ei + E;
  const int NB = (N + 1023) >> 10;  // 49 coarse buckets

  char* base = (char*)d_ws;
  size_t o = 0;
  auto alloc = [&](size_t bytes) {
    void* p = base + o;
    o = (o + bytes + 255) & ~(size_t)255;
    return p;
  };
  int* bucket_cnt = (int*)alloc((size_t)NBMAX * 4);              // 256 B
  unsigned int* bkt = (unsigned int*)alloc((size_t)NBMAX * BCAP * 4);  // 6.3 MB
  int* cnt = (int*)alloc((size_t)N * 4);                         // 0.2 MB
  ushort* csr_pad = (ushort*)alloc((size_t)N * CAP * 2);         // 6.4 MB
  ushort* hf1 = (ushort*)alloc((size_t)N * D * 2);               // 12.8 MB
  ushort* hf2 = (ushort*)alloc((size_t)N * D * 2);               // 12.8 MB
  ushort* h1 = (ushort*)alloc((size_t)N * D * 2);                // 12.8 MB
  ushort* asrc1 = (ushort*)alloc((size_t)N * 8 * 2);             // 0.8 MB
  ushort* asrc2 = (ushort*)alloc((size_t)N * 8 * 2);             // 0.8 MB
  float* adst1 = (float*)alloc((size_t)N * 8 * 4);               // 1.6 MB
  float* adst2 = (float*)alloc((size_t)N * 8 * 4);               // 1.6 MB
  ushort* wp1 = (ushort*)alloc((size_t)WPACK * 2);               // 36 KB
  ushort* wp2 = (ushort*)alloc((size_t)WPACK * 2);               // 36 KB

  int gemm_blocks = (N + 127) / 128;

  // K1: pack W1+Va1, W2+Va2; zero bucket_cnt
  pack_all_kernel<<<(2 * WPACK + 255) / 256, 256, 0, stream>>>(
      W1, as1, ad1, wp1, W2, as2, ad2, wp2, bucket_cnt);
  // K2: phase-1 coarse bucket scatter
  bucket_kernel<<<(E + EPB - 1) / EPB, 256, 0, stream>>>(row, col, bucket_cnt, bkt, E, NB);
  // K3: phase-2 CSR build (NB blocks) + gemm1 (grid-fused)
  csr_gemm_kernel<<<NB + gemm_blocks, 256, 0, stream>>>(
      x, wp1, hf1, asrc1, adst1, N, bkt, bucket_cnt, cnt, csr_pad, NB);
  // K4: aggregate layer 1 + fused gemm2
  agg_gemm_kernel<<<(N + 31) / 32, 256, 0, stream>>>(
      hf1, asrc1, adst1, cnt, csr_pad, b1, wp2, h1, hf2, asrc2, adst2, N);
  // K5: aggregate layer 2 -> out = x + h1 + h2
  aggregate2_kernel<<<(N + 3) / 4, 256, 0, stream>>>(
      hf2, asrc2, adst2, cnt, csr_pad, b2, x, h1, out, N);
}

// Round 8
// 230.402 us; speedup vs baseline: 1.1296x; 1.1296x over previous
//
#include <hip/hip_runtime.h>
#include <hip/hip_bf16.h>
#include <math.h>

// GAT structural encoder: out = x + h1 + h2
//   h1 = relu(gat(x;  W1,a_src1,a_dst1,b1))
//   h2 = relu(gat(h1; W2,a_src2,a_dst2,b2))
// Round-8 design:
//  - two-phase CSR build (r7, kept): coarse 1024-dst buckets w/ LDS histograms,
//    then one block per bucket -> csr lines dirtied once. Phase-2 grid-fused
//    with gemm1.
//  - gemm2 UN-fused (r7 regression): wave-per-dst aggregate restored (12500
//    waves of gather TLP), separate 15us MFMA gemm2 dispatch.
//  - aggregate gather: 8-way edge unroll -> ~17 loads in flight per wave.
//  - GEMM via v_mfma_f32_16x16x32_bf16; W pre-packed fragment-order; 9th
//    col-tile = [W@a_src | W@a_dst] so logits fall out of MFMA accumulators.
// Fragment layout (verified refs in guide): A: row=lane&15, k=8*(lane>>4)+e;
// B: col=lane&15, k=8*(lane>>4)+e; C/D: col=lane&15, row=4*(lane>>4)+reg.

constexpr int D = 128;
constexpr int CAP = 64;       // max in-degree (multinomial mean 16, max ~35)
constexpr int WPACK = 18432;  // packed W elems: 16384 (W) + 2048 (Va)
constexpr int NBMAX = 64;     // max coarse buckets
constexpr int BCAP = 24576;   // edges per coarse bucket capacity (mean ~16.3k)
constexpr int EPB = 4096;     // edges per phase-1 block

using bf16x8 = __attribute__((ext_vector_type(8))) short;
using f32x4 = __attribute__((ext_vector_type(4))) float;

static __device__ __forceinline__ float lrelu(float v) {
  return v > 0.f ? v : 0.2f * v;
}

static __device__ __forceinline__ ushort bfbits(float f) {
  __hip_bfloat16 b = __float2bfloat16(f);
  return *reinterpret_cast<ushort*>(&b);
}

static __device__ __forceinline__ float bf2f(ushort u) {
  union { unsigned int u; float f; } c;
  c.u = (unsigned int)u << 16;
  return c.f;
}

// ---------------- K1: pack W1/W2 into fragment order; zero bucket_cnt --------
// idx<16384: Wp[ks][g][ct][c][e] = W[ks*32+g*8+e][ct*16+c]
// idx>=16384: Va block [ks][g][c][e]: c<8 -> head c of W@a_src; c>=8 -> W@a_dst
__global__ void pack_all_kernel(const float* __restrict__ W1, const float* __restrict__ as1,
                                const float* __restrict__ ad1, ushort* __restrict__ wp1,
                                const float* __restrict__ W2, const float* __restrict__ as2,
                                const float* __restrict__ ad2, ushort* __restrict__ wp2,
                                int* __restrict__ bucket_cnt) {
  int t = blockIdx.x * blockDim.x + threadIdx.x;
  if (t < NBMAX) bucket_cnt[t] = 0;
  const float *W, *as_, *ad_;
  ushort* wp;
  int idx;
  if (t < WPACK) {
    W = W1; as_ = as1; ad_ = ad1; wp = wp1; idx = t;
  } else if (t < 2 * WPACK) {
    W = W2; as_ = as2; ad_ = ad2; wp = wp2; idx = t - WPACK;
  } else {
    return;
  }
  if (idx < 16384) {
    int e = idx & 7, c = (idx >> 3) & 15, ct = (idx >> 7) & 7, g = (idx >> 10) & 3,
        ks = idx >> 12;
    int k = ks * 32 + g * 8 + e, n = ct * 16 + c;
    wp[idx] = bfbits(W[k * 128 + n]);
  } else {
    int j = idx - 16384;
    int e = j & 7, c = (j >> 3) & 15, g = (j >> 7) & 3, ks = j >> 9;
    int k = ks * 32 + g * 8 + e;
    int h = c & 7;
    const float* a = (c >> 3) ? ad_ : as_;
    float s = 0.f;
    #pragma unroll
    for (int cc = 0; cc < 16; ++cc) s += W[k * 128 + h * 16 + cc] * a[h * 16 + cc];
    wp[idx] = bfbits(s);
  }
}

// ---------------- K2: phase-1 bucket scatter ----------------
// Pack (dstLow10 << 16 | row16) into per-bucket regions; runs are sequential.
__global__ __launch_bounds__(256) void bucket_kernel(
    const int* __restrict__ row, const int* __restrict__ col,
    int* __restrict__ bucket_cnt, unsigned int* __restrict__ bkt, int E, int NB) {
  __shared__ int hist[NBMAX];
  __shared__ int base_s[NBMAX];
  int tid = threadIdx.x;
  if (tid < NBMAX) hist[tid] = 0;
  __syncthreads();
  int e0 = blockIdx.x * EPB;
  unsigned int uv[16];
  int bb[16], rr[16];
  #pragma unroll
  for (int j = 0; j < 16; ++j) {
    int e = e0 + j * 256 + tid;
    bb[j] = -1; uv[j] = 0; rr[j] = 0;
    if (e < E) {
      int c = col[e], r = row[e];
      bb[j] = c >> 10;
      uv[j] = ((unsigned int)(c & 1023) << 16) | (unsigned int)r;
      rr[j] = atomicAdd(&hist[bb[j]], 1);
    }
  }
  __syncthreads();
  if (tid < NB) base_s[tid] = atomicAdd(&bucket_cnt[tid], hist[tid]);
  __syncthreads();
  #pragma unroll
  for (int j = 0; j < 16; ++j) {
    if (bb[j] >= 0) {
      int pos = base_s[bb[j]] + rr[j];
      if (pos < BCAP) bkt[(size_t)bb[j] * BCAP + pos] = uv[j];
    }
  }
}

// ---------------- K3: phase-2 CSR build (blocks < NB) + gemm1 ----------------
__global__ __launch_bounds__(256) void csr_gemm_kernel(
    const float* __restrict__ X, const ushort* __restrict__ Wp,
    ushort* __restrict__ Hf, ushort* __restrict__ asrc, float* __restrict__ adst,
    int N, const unsigned int* __restrict__ bkt, const int* __restrict__ bucket_cnt,
    int* __restrict__ cnt, ushort* __restrict__ csr_pad, int NB) {
  __shared__ ushort Wl[WPACK];  // 36 KB (phase-2 blocks alias 4 KB of it)
  int tid = threadIdx.x;
  if ((int)blockIdx.x < NB) {
    int b = blockIdx.x;
    int* lcnt = (int*)Wl;
    for (int i = tid; i < 1024; i += 256) lcnt[i] = 0;
    __syncthreads();
    int ce = min(bucket_cnt[b], BCAP);
    const unsigned int* bp = bkt + (size_t)b * BCAP;
    for (int i = tid; i < ce; i += 256) {
      unsigned int u = bp[i];
      int dl = u >> 16;
      int p = atomicAdd(&lcnt[dl], 1);
      if (p < CAP) csr_pad[((size_t)((b << 10) + dl)) * CAP + p] = (ushort)(u & 0xffffu);
    }
    __syncthreads();
    int nd = min(1024, N - (b << 10));
    for (int i = tid; i < nd; i += 256) cnt[(b << 10) + i] = lcnt[i];
    return;
  }

  // ---- gemm1: X(f32) @ W1 -> Hf(bf16) + logits ----
  for (int i = tid; i < WPACK / 8; i += 256)
    *(uint4*)&Wl[i * 8] = *(const uint4*)&Wp[i * 8];
  __syncthreads();

  int lane = tid & 63, w = tid >> 6;
  int g = lane >> 4, c = lane & 15;
  int rt0 = ((int)blockIdx.x - NB) * 128 + w * 32;

  f32x4 acc[2][9];
  #pragma unroll
  for (int rt = 0; rt < 2; ++rt)
    #pragma unroll
    for (int ct = 0; ct < 9; ++ct) acc[rt][ct] = (f32x4)0.f;

  #pragma unroll
  for (int ks = 0; ks < 4; ++ks) {
    bf16x8 a[2];
    #pragma unroll
    for (int rt = 0; rt < 2; ++rt) {
      int r = rt0 + rt * 16 + c;
      if (r < N) {
        const float* xp = &X[(size_t)r * D + ks * 32 + g * 8];
        float4 x0 = *(const float4*)xp;
        float4 x1 = *(const float4*)(xp + 4);
        bf16x8 t;
        t[0] = (short)bfbits(x0.x); t[1] = (short)bfbits(x0.y);
        t[2] = (short)bfbits(x0.z); t[3] = (short)bfbits(x0.w);
        t[4] = (short)bfbits(x1.x); t[5] = (short)bfbits(x1.y);
        t[6] = (short)bfbits(x1.z); t[7] = (short)bfbits(x1.w);
        a[rt] = t;
      } else {
        a[rt] = (bf16x8)(short)0;
      }
    }
    #pragma unroll
    for (int ct = 0; ct < 9; ++ct) {
      const ushort* bp = (ct < 8)
          ? &Wl[(size_t)(((ks * 4 + g) * 8 + ct) * 16 + c) * 8]
          : &Wl[16384 + (size_t)((ks * 4 + g) * 16 + c) * 8];
      bf16x8 b = *(const bf16x8*)bp;
      acc[0][ct] = __builtin_amdgcn_mfma_f32_16x16x32_bf16(a[0], b, acc[0][ct], 0, 0, 0);
      acc[1][ct] = __builtin_amdgcn_mfma_f32_16x16x32_bf16(a[1], b, acc[1][ct], 0, 0, 0);
    }
  }

  #pragma unroll
  for (int rt = 0; rt < 2; ++rt) {
    #pragma unroll
    for (int j = 0; j < 4; ++j) {
      int r = rt0 + rt * 16 + g * 4 + j;
      if (r >= N) continue;
      #pragma unroll
      for (int ct = 0; ct < 8; ++ct)
        Hf[(size_t)r * D + ct * 16 + c] = bfbits(acc[rt][ct][j]);
      float lv = acc[rt][8][j];
      if (c < 8) asrc[r * 8 + c] = bfbits(lv);
      else adst[r * 8 + (c - 8)] = lv;
    }
  }
}

// ---------------- K5: standalone gemm2 (h1 bf16 -> Hf + logits) ----------------
__global__ __launch_bounds__(256) void gemm2_kernel(
    const ushort* __restrict__ Xv, const ushort* __restrict__ Wp,
    ushort* __restrict__ Hf, ushort* __restrict__ asrc, float* __restrict__ adst,
    int N) {
  __shared__ ushort Wl[WPACK];  // 36 KB
  int tid = threadIdx.x;
  for (int i = tid; i < WPACK / 8; i += 256)
    *(uint4*)&Wl[i * 8] = *(const uint4*)&Wp[i * 8];
  __syncthreads();

  int lane = tid & 63, w = tid >> 6;
  int g = lane >> 4, c = lane & 15;
  int rt0 = blockIdx.x * 128 + w * 32;

  f32x4 acc[2][9];
  #pragma unroll
  for (int rt = 0; rt < 2; ++rt)
    #pragma unroll
    for (int ct = 0; ct < 9; ++ct) acc[rt][ct] = (f32x4)0.f;

  #pragma unroll
  for (int ks = 0; ks < 4; ++ks) {
    bf16x8 a[2];
    #pragma unroll
    for (int rt = 0; rt < 2; ++rt) {
      int r = rt0 + rt * 16 + c;
      a[rt] = (r < N) ? *(const bf16x8*)&Xv[(size_t)r * D + ks * 32 + g * 8]
                      : (bf16x8)(short)0;
    }
    #pragma unroll
    for (int ct = 0; ct < 9; ++ct) {
      const ushort* bp = (ct < 8)
          ? &Wl[(size_t)(((ks * 4 + g) * 8 + ct) * 16 + c) * 8]
          : &Wl[16384 + (size_t)((ks * 4 + g) * 16 + c) * 8];
      bf16x8 b = *(const bf16x8*)bp;
      acc[0][ct] = __builtin_amdgcn_mfma_f32_16x16x32_bf16(a[0], b, acc[0][ct], 0, 0, 0);
      acc[1][ct] = __builtin_amdgcn_mfma_f32_16x16x32_bf16(a[1], b, acc[1][ct], 0, 0, 0);
    }
  }

  #pragma unroll
  for (int rt = 0; rt < 2; ++rt) {
    #pragma unroll
    for (int j = 0; j < 4; ++j) {
      int r = rt0 + rt * 16 + g * 4 + j;
      if (r >= N) continue;
      #pragma unroll
      for (int ct = 0; ct < 8; ++ct)
        Hf[(size_t)r * D + ct * 16 + c] = bfbits(acc[rt][ct][j]);
      float lv = acc[rt][8][j];
      if (c < 8) asrc[r * 8 + c] = bfbits(lv);
      else adst[r * 8 + (c - 8)] = lv;
    }
  }
}

// ---------------- gather: softmax-weighted neighbor sum, 8-way unroll --------
static __device__ __forceinline__ void gather_node(
    const ushort* __restrict__ Hf, const ushort* __restrict__ asrc, float adst_h,
    const int* __restrict__ cnt, const ushort* __restrict__ csr_pad,
    int dst, int h, int d0, float& accx, float& accy, float& wsum) {
  float ws = __expf(lrelu(bf2f(asrc[dst * 8 + h]) + adst_h));  // self loop
  ushort2 fs = *(const ushort2*)&Hf[(size_t)dst * D + d0];
  accx = ws * bf2f(fs.x); accy = ws * bf2f(fs.y); wsum = ws;
  int cn = min(cnt[dst], CAP);
  const ushort* cp = csr_pad + (size_t)dst * CAP;
  int i = 0;
  for (; i + 8 <= cn; i += 8) {
    ushort4 sa = *(const ushort4*)(cp + i);
    ushort4 sb = *(const ushort4*)(cp + i + 4);
    int s[8] = {sa.x, sa.y, sa.z, sa.w, sb.x, sb.y, sb.z, sb.w};
    float l[8];
    ushort2 f[8];
    #pragma unroll
    for (int j = 0; j < 8; ++j) l[j] = bf2f(asrc[s[j] * 8 + h]);
    #pragma unroll
    for (int j = 0; j < 8; ++j) f[j] = *(const ushort2*)&Hf[(size_t)s[j] * D + d0];
    #pragma unroll
    for (int j = 0; j < 8; ++j) {
      float we = __expf(lrelu(l[j] + adst_h));
      accx += we * bf2f(f[j].x);
      accy += we * bf2f(f[j].y);
      wsum += we;
    }
  }
  for (; i + 4 <= cn; i += 4) {
    ushort4 s4 = *(const ushort4*)(cp + i);
    int s[4] = {s4.x, s4.y, s4.z, s4.w};
    float l[4];
    ushort2 f[4];
    #pragma unroll
    for (int j = 0; j < 4; ++j) l[j] = bf2f(asrc[s[j] * 8 + h]);
    #pragma unroll
    for (int j = 0; j < 4; ++j) f[j] = *(const ushort2*)&Hf[(size_t)s[j] * D + d0];
    #pragma unroll
    for (int j = 0; j < 4; ++j) {
      float we = __expf(lrelu(l[j] + adst_h));
      accx += we * bf2f(f[j].x);
      accy += we * bf2f(f[j].y);
      wsum += we;
    }
  }
  for (; i < cn; ++i) {
    int src = cp[i];
    float we = __expf(lrelu(bf2f(asrc[src * 8 + h]) + adst_h));
    ushort2 fv = *(const ushort2*)&Hf[(size_t)src * D + d0];
    accx += we * bf2f(fv.x);
    accy += we * bf2f(fv.y);
    wsum += we;
  }
}

// ---------------- K4/K6: aggregation, one wave per destination node ----------
// lane owns channels 2l,2l+1 (head h=l>>3).
template <int LAYER>
__global__ __launch_bounds__(256) void aggregate_kernel(
    const ushort* __restrict__ Hf, const ushort* __restrict__ asrc,
    const float* __restrict__ adst, const int* __restrict__ cnt,
    const ushort* __restrict__ csr_pad, const float* __restrict__ bias,
    const float* __restrict__ xin, const ushort* __restrict__ h1in,
    void* __restrict__ outp, int N) {
  int wid = (blockIdx.x * blockDim.x + threadIdx.x) >> 6;
  if (wid >= N) return;
  int lane = threadIdx.x & 63;
  int h = lane >> 3, d0 = lane * 2;
  int dst = wid;
  float adh = adst[dst * 8 + h];
  float ax, ay, wsm;
  gather_node(Hf, asrc, adh, cnt, csr_pad, dst, h, d0, ax, ay, wsm);
  float inv = 1.f / (wsm + 1e-16f);
  float2 bv = *(const float2*)&bias[d0];
  float r0 = fmaxf(ax * inv + bv.x, 0.f);
  float r1 = fmaxf(ay * inv + bv.y, 0.f);
  if (LAYER == 1) {
    ushort2 u;
    u.x = bfbits(r0); u.y = bfbits(r1);
    *(ushort2*)&((ushort*)outp)[(size_t)dst * D + d0] = u;   // h1 bf16
  } else {
    float2 xv = *(const float2*)&xin[(size_t)dst * D + d0];
    ushort2 hv = *(const ushort2*)&h1in[(size_t)dst * D + d0];
    *(float2*)&((float*)outp)[(size_t)dst * D + d0] =
        make_float2(xv.x + bf2f(hv.x) + r0, xv.y + bf2f(hv.y) + r1);
  }
}

extern "C" void kernel_launch(void* const* d_in, const int* in_sizes, int n_in,
                              void* d_out, int out_size, void* d_ws, size_t ws_size,
                              hipStream_t stream) {
  const float* x = (const float*)d_in[0];
  const int* ei = (const int*)d_in[1];
  const float* W1 = (const float*)d_in[3];
  const float* as1 = (const float*)d_in[4];
  const float* ad1 = (const float*)d_in[5];
  const float* b1 = (const float*)d_in[6];
  const float* W2 = (const float*)d_in[7];
  const float* as2 = (const float*)d_in[8];
  const float* ad2 = (const float*)d_in[9];
  const float* b2 = (const float*)d_in[10];
  float* out = (float*)d_out;

  const int N = in_sizes[0] / D;   // 50000 (< 65536: ushort node IDs)
  const int E = in_sizes[1] / 2;
  const int* row = ei;
  const int* col = ei + E;
  const int NB = (N + 1023) >> 10;  // 49 coarse buckets

  char* base = (char*)d_ws;
  size_t o = 0;
  auto alloc = [&](size_t bytes) {
    void* p = base + o;
    o = (o + bytes + 255) & ~(size_t)255;
    return p;
  };
  int* bucket_cnt = (int*)alloc((size_t)NBMAX * 4);                    // 256 B
  unsigned int* bkt = (unsigned int*)alloc((size_t)NBMAX * BCAP * 4);  // 6.3 MB
  int* cnt = (int*)alloc((size_t)N * 4);                               // 0.2 MB
  ushort* csr_pad = (ushort*)alloc((size_t)N * CAP * 2);               // 6.4 MB
  ushort* hf = (ushort*)alloc((size_t)N * D * 2);                      // 12.8 MB
  ushort* h1 = (ushort*)alloc((size_t)N * D * 2);                      // 12.8 MB
  ushort* asrcb = (ushort*)alloc((size_t)N * 8 * 2);                   // 0.8 MB
  float* adstb = (float*)alloc((size_t)N * 8 * 4);                     // 1.6 MB
  ushort* wp1 = (ushort*)alloc((size_t)WPACK * 2);                     // 36 KB
  ushort* wp2 = (ushort*)alloc((size_t)WPACK * 2);                     // 36 KB

  int gemm_blocks = (N + 127) / 128;
  int agg_blocks = (N + 3) / 4;

  // K1: pack W1+Va1, W2+Va2; zero bucket_cnt
  pack_all_kernel<<<(2 * WPACK + 255) / 256, 256, 0, stream>>>(
      W1, as1, ad1, wp1, W2, as2, ad2, wp2, bucket_cnt);
  // K2: phase-1 coarse bucket scatter
  bucket_kernel<<<(E + EPB - 1) / EPB, 256, 0, stream>>>(row, col, bucket_cnt, bkt, E, NB);
  // K3: phase-2 CSR build (NB blocks) + gemm1 (grid-fused)
  csr_gemm_kernel<<<NB + gemm_blocks, 256, 0, stream>>>(
      x, wp1, hf, asrcb, adstb, N, bkt, bucket_cnt, cnt, csr_pad, NB);
  // K4: aggregate layer 1 -> h1 (bf16)
  aggregate_kernel<1><<<agg_blocks, 256, 0, stream>>>(
      hf, asrcb, adstb, cnt, csr_pad, b1, nullptr, nullptr, h1, N);
  // K5: gemm2 (MFMA) h1 -> hf + logits
  gemm2_kernel<<<gemm_blocks, 256, 0, stream>>>(h1, wp2, hf, asrcb, adstb, N);
  // K6: aggregate layer 2 -> out = x + h1 + h2
  aggregate_kernel<2><<<agg_blocks, 256, 0, stream>>>(
      hf, asrcb, adstb, cnt, csr_pad, b2, x, h1, out, N);
}